// Round 8
// baseline (278.026 us; speedup 1.0000x reference)
//
#include <hip/hip_runtime.h>
#include <hip/hip_fp16.h>

#define NN 50000
#define NE 800000
#define D  96
#define NB_SCAN 196   // ceil(NN/256)
#define N4 (NN * D / 4)
#define CB4 ((N4 + 255) / 256)
#define WFRAG_BLKS 5  // ceil(18*64/256)

typedef unsigned int   uint32;
typedef unsigned short uint16;
typedef short  v8s __attribute__((ext_vector_type(8)));  // 8 bf16 (4 VGPRs)
typedef float  v4f __attribute__((ext_vector_type(4)));  // MFMA accumulator
typedef unsigned int v2u __attribute__((ext_vector_type(2)));  // clang vec, ok for nontemporal builtins

__device__ inline uint16 f32_to_bf16(float f) {          // round-nearest-even
    uint32 u = __float_as_uint(f);
    u += 0x7FFF + ((u >> 16) & 1);
    return (uint16)(u >> 16);
}

// unpack 4 bf16 (packed in v2u) -> 4 floats
__device__ inline void u2f(v2u u, float& a, float& b, float& c, float& d) {
    a = __uint_as_float(u.x << 16);
    b = __uint_as_float(u.x & 0xFFFF0000u);
    c = __uint_as_float(u.y << 16);
    d = __uint_as_float(u.y & 0xFFFF0000u);
}

__device__ inline float f16_val(uint32 e) {
    __half_raw h; h.x = (uint16)(e >> 16);
    return __half2float(__half(h));
}

// ---- fused prep: H->bf16 | zero counts | W->B-fragment layout ----
__global__ void prep(const float4* __restrict__ H, ushort4* __restrict__ Hb,
                     const float* __restrict__ W, uint16* __restrict__ Wfrag,
                     int* __restrict__ counts) {
    int b = blockIdx.x;
    int t = threadIdx.x;
    if (b < CB4) {
        int i = b * 256 + t;
        if (i < N4) {
            float4 v = H[i];
            ushort4 o;
            o.x = f32_to_bf16(v.x); o.y = f32_to_bf16(v.y);
            o.z = f32_to_bf16(v.z); o.w = f32_to_bf16(v.w);
            Hb[i] = o;
        }
    } else if (b < CB4 + NB_SCAN) {
        int i = (b - CB4) * 256 + t;
        if (i < NN) counts[i] = 0;
    } else {
        int idx = (b - CB4 - NB_SCAN) * 256 + t;   // 0..1151 = bt*64+lane
        if (idx < 18 * 64) {
            int bt = idx >> 6, lane = idx & 63;
            int nt = bt / 3, kc = bt % 3;
            int col = nt * 16 + (lane & 15);
            int kbase = kc * 32 + (lane >> 4) * 8;
            uint16 tmp[8];
            #pragma unroll
            for (int j = 0; j < 8; ++j) tmp[j] = f32_to_bf16(W[(kbase + j) * D + col]);
            uint32* dst = (uint32*)(Wfrag + ((size_t)bt * 64 + lane) * 8);
            const uint32* src = (const uint32*)tmp;
            #pragma unroll
            for (int j = 0; j < 4; ++j) dst[j] = src[j];
        }
    }
}

// ---------------- CSR build (slot-free) ----------------
__global__ void hist(const int* __restrict__ rows, int* __restrict__ counts) {
    int e = blockIdx.x * blockDim.x + threadIdx.x;
    if (e < NE) atomicAdd(&counts[rows[e]], 1);
}

__global__ void scan_p1(const int* __restrict__ counts, int* __restrict__ partials) {
    __shared__ int red[256];
    int t = threadIdx.x;
    int i = blockIdx.x * 256 + t;
    red[t] = (i < NN) ? counts[i] : 0;
    __syncthreads();
    for (int off = 128; off > 0; off >>= 1) {
        if (t < off) red[t] += red[t + off];
        __syncthreads();
    }
    if (t == 0) partials[blockIdx.x] = red[0];
}

// each block scans partials redundantly + local scan; writes row_ptr AND
// rewrites counts[i] = row start (cursor for fill_edges).
__global__ void scan_p23(int* __restrict__ counts, const int* __restrict__ partials,
                         int* __restrict__ row_ptr) {
    __shared__ int pp[256];
    __shared__ int sh[256];
    int t = threadIdx.x;
    pp[t] = (t < NB_SCAN) ? partials[t] : 0;
    __syncthreads();
    for (int off = 1; off < 256; off <<= 1) {
        int u = (t >= off) ? pp[t - off] : 0;
        __syncthreads();
        pp[t] += u;
        __syncthreads();
    }
    int blk_off = (blockIdx.x == 0) ? 0 : pp[blockIdx.x - 1];
    int i = blockIdx.x * 256 + t;
    int v = (i < NN) ? counts[i] : 0;
    sh[t] = v;
    __syncthreads();
    for (int off = 1; off < 256; off <<= 1) {
        int u = (t >= off) ? sh[t - off] : 0;
        __syncthreads();
        sh[t] += u;
        __syncthreads();
    }
    int excl = sh[t] - v + blk_off;
    if (i < NN) { row_ptr[i] = excl; counts[i] = excl; }
    if (i == NN - 1) row_ptr[NN] = excl + v;
}

// edge = col (low 16) | f16(val) (high 16); position from cursor atomics
__global__ void fill_edges(const int* __restrict__ rows, const int* __restrict__ cols,
                           const float* __restrict__ vals, int* __restrict__ cursor,
                           uint32* __restrict__ edges) {
    int e = blockIdx.x * blockDim.x + threadIdx.x;
    if (e < NE) {
        int p = atomicAdd(&cursor[rows[e]], 1);
        __half_raw hr = __half_raw(__float2half(vals[e]));
        edges[p] = (uint32)(cols[e] & 0xFFFF) | ((uint32)hr.x << 16);
    }
}

// ---- SpMM (all bf16): Yb = bf16( ca*A + cb*B + scale * sum val * Xb[col] ) --
// 32 lanes per row; lanes 0..23 own 4 feats (8 B loads). Streams (A,B reads,
// Yb write) are nontemporal to keep Xb resident in L2 for the gathers.
__global__ void spmm(const int* __restrict__ row_ptr, const uint32* __restrict__ edges,
                     const uint16* __restrict__ Xb, const uint16* __restrict__ A,
                     const uint16* __restrict__ B, uint16* __restrict__ Yb,
                     float scale, float ca, float cb) {
    int tid  = threadIdx.x;
    int lane = tid & 31;
    int g    = tid >> 5;
    int r = blockIdx.x * 8 + g;
    if (r >= NN) return;
    if (lane >= 24) return;                       // exec-masked idle lanes

    const v2u* xbase = (const v2u*)Xb;            // row stride = 24 v2u

    v2u av = __builtin_nontemporal_load((const v2u*)(A + (size_t)r * D) + lane);
    v2u bv = __builtin_nontemporal_load((const v2u*)(B + (size_t)r * D) + lane);
    float a0,a1,a2,a3,b0,b1,b2,b3;
    u2f(av, a0,a1,a2,a3);
    u2f(bv, b0,b1,b2,b3);
    float ax = ca*a0 + cb*b0;
    float ay = ca*a1 + cb*b1;
    float az = ca*a2 + cb*b2;
    float aw = ca*a3 + cb*b3;

    int s = row_ptr[r];
    int e = row_ptr[r + 1];
    int i = s;
    for (; i + 7 < e; i += 8) {
        uint32 ee[8];
        #pragma unroll
        for (int j = 0; j < 8; ++j) ee[j] = edges[i + j];
        v2u xx[8];
        #pragma unroll
        for (int j = 0; j < 8; ++j)
            xx[j] = xbase[(size_t)(ee[j] & 0xFFFF) * 24 + lane];
        #pragma unroll
        for (int j = 0; j < 8; ++j) {
            float v = scale * f16_val(ee[j]);
            float x0,x1,x2,x3;
            u2f(xx[j], x0,x1,x2,x3);
            ax += v*x0; ay += v*x1; az += v*x2; aw += v*x3;
        }
    }
    for (; i + 3 < e; i += 4) {
        uint32 ee[4];
        #pragma unroll
        for (int j = 0; j < 4; ++j) ee[j] = edges[i + j];
        v2u xx[4];
        #pragma unroll
        for (int j = 0; j < 4; ++j)
            xx[j] = xbase[(size_t)(ee[j] & 0xFFFF) * 24 + lane];
        #pragma unroll
        for (int j = 0; j < 4; ++j) {
            float v = scale * f16_val(ee[j]);
            float x0,x1,x2,x3;
            u2f(xx[j], x0,x1,x2,x3);
            ax += v*x0; ay += v*x1; az += v*x2; aw += v*x3;
        }
    }
    for (; i < e; ++i) {
        uint32 e0 = edges[i];
        float v = scale * f16_val(e0);
        v2u x = xbase[(size_t)(e0 & 0xFFFF) * 24 + lane];
        float x0,x1,x2,x3;
        u2f(x, x0,x1,x2,x3);
        ax += v*x0; ay += v*x1; az += v*x2; aw += v*x3;
    }

    v2u o;
    o.x = (uint32)f32_to_bf16(ax) | ((uint32)f32_to_bf16(ay) << 16);
    o.y = (uint32)f32_to_bf16(az) | ((uint32)f32_to_bf16(aw) << 16);
    __builtin_nontemporal_store(o, (v2u*)(Yb + (size_t)r * D) + lane);
}

// ---- out = Sb @ W + bias via MFMA; one wave per 16-row strip (grid-stride) --
__global__ void mfma_gemm(const uint16* __restrict__ Sb, const uint16* __restrict__ Wfrag,
                          const float* __restrict__ bias, float* __restrict__ out) {
    int tid   = threadIdx.x;
    int lane  = tid & 63;
    int wv    = blockIdx.x * (blockDim.x >> 6) + (tid >> 6);
    int nwv   = gridDim.x * (blockDim.x >> 6);
    int col   = lane & 15;
    int quad  = lane >> 4;

    v8s wf[6][3];
    #pragma unroll
    for (int nt = 0; nt < 6; ++nt)
        #pragma unroll
        for (int kc = 0; kc < 3; ++kc)
            wf[nt][kc] = ((const v8s*)Wfrag)[(nt * 3 + kc) * 64 + lane];

    float bi[6];
    #pragma unroll
    for (int nt = 0; nt < 6; ++nt) bi[nt] = bias[nt * 16 + col];

    for (int s = wv; s < NN / 16; s += nwv) {
        int r0 = s * 16;
        const uint16* arow = Sb + (size_t)(r0 + col) * D + quad * 8;
        v8s a0 = *((const v8s*)(arow));
        v8s a1 = *((const v8s*)(arow + 32));
        v8s a2 = *((const v8s*)(arow + 64));
        v4f acc[6];
        #pragma unroll
        for (int nt = 0; nt < 6; ++nt) {
            v4f c = {0.f, 0.f, 0.f, 0.f};
            c = __builtin_amdgcn_mfma_f32_16x16x32_bf16(a0, wf[nt][0], c, 0, 0, 0);
            c = __builtin_amdgcn_mfma_f32_16x16x32_bf16(a1, wf[nt][1], c, 0, 0, 0);
            c = __builtin_amdgcn_mfma_f32_16x16x32_bf16(a2, wf[nt][2], c, 0, 0, 0);
            acc[nt] = c;
        }
        #pragma unroll
        for (int nt = 0; nt < 6; ++nt) {
            float* o = out + (size_t)(r0 + quad * 4) * D + nt * 16 + col;
            o[0 * D] = acc[nt][0] + bi[nt];
            o[1 * D] = acc[nt][1] + bi[nt];
            o[2 * D] = acc[nt][2] + bi[nt];
            o[3 * D] = acc[nt][3] + bi[nt];
        }
    }
}

extern "C" void kernel_launch(void* const* d_in, const int* in_sizes, int n_in,
                              void* d_out, int out_size, void* d_ws, size_t ws_size,
                              hipStream_t stream) {
    const int*   rows = (const int*)d_in[0];
    const int*   cols = (const int*)d_in[1];
    const float* vals = (const float*)d_in[2];
    const float* H    = (const float*)d_in[3];
    const float* W    = (const float*)d_in[4];
    const float* bias = (const float*)d_in[5];
    float* out = (float*)d_out;

    char* ws = (char*)d_ws;
    uint16* Hb       = (uint16*)ws;  ws += (size_t)NN * D * 2;   // 9.6 MB
    uint16* T1b      = (uint16*)ws;  ws += (size_t)NN * D * 2;   // later Sb
    uint16* T2b      = (uint16*)ws;  ws += (size_t)NN * D * 2;
    uint32* edges    = (uint32*)ws;  ws += (size_t)NE * 4;       // 3.2 MB
    uint16* Wfrag    = (uint16*)ws;  ws += (size_t)18 * 64 * 8 * 2;
    int*    counts   = (int*)ws;     ws += (size_t)NN * 4;       // also cursor
    int*    row_ptr  = (int*)ws;     ws += (size_t)(NN + 1) * 4;
    int*    partials = (int*)ws;     ws += 256 * 4;
    uint16* Sb       = T1b;          // T1b dead after pass 2 reads it

    const int eb = (NE + 255) / 256;

    prep<<<CB4 + NB_SCAN + WFRAG_BLKS, 256, 0, stream>>>(
        (const float4*)H, (ushort4*)Hb, W, Wfrag, counts);
    hist<<<eb, 256, 0, stream>>>(rows, counts);
    scan_p1<<<NB_SCAN, 256, 0, stream>>>(counts, partials);
    scan_p23<<<NB_SCAN, 256, 0, stream>>>(counts, partials, row_ptr);
    fill_edges<<<eb, 256, 0, stream>>>(rows, cols, vals, counts, edges);

    const int sb = (NN + 7) / 8;

    // T1 = 2*spmm(H) - H
    spmm<<<sb, 256, 0, stream>>>(row_ptr, edges, Hb, Hb, Hb, T1b, 2.0f, -1.0f, 0.0f);
    // T2 = 4*spmm(T1) - 2*T1 - H
    spmm<<<sb, 256, 0, stream>>>(row_ptr, edges, T1b, T1b, Hb, T2b, 4.0f, -2.0f, -1.0f);
    // Sb = 4*spmm(T2) + H - T2   (= H+T1+T2+T3)
    spmm<<<sb, 256, 0, stream>>>(row_ptr, edges, T2b, Hb, T2b, Sb, 4.0f, 1.0f, -1.0f);
    // out = Sb @ W + bias  (MFMA)
    mfma_gemm<<<391, 256, 0, stream>>>(Sb, Wfrag, bias, out);
}

// Round 9
// 237.183 us; speedup vs baseline: 1.1722x; 1.1722x over previous
//
#include <hip/hip_runtime.h>
#include <hip/hip_fp16.h>

#define NN 50000
#define NE 800000
#define D  96
#define NB_SCAN 196   // ceil(NN/256)
#define N4 (NN * D / 4)
#define CB4 ((N4 + 255) / 256)
#define WFRAG_BLKS 5  // ceil(18*64/256)

typedef unsigned int   uint32;
typedef unsigned short uint16;
typedef short  v8s __attribute__((ext_vector_type(8)));  // 8 bf16 (4 VGPRs)
typedef float  v4f __attribute__((ext_vector_type(4)));  // MFMA accumulator
typedef unsigned int v2u __attribute__((ext_vector_type(2)));  // clang vec for nontemporal builtins

__device__ inline uint16 f32_to_bf16(float f) {          // round-nearest-even
    uint32 u = __float_as_uint(f);
    u += 0x7FFF + ((u >> 16) & 1);
    return (uint16)(u >> 16);
}

// unpack 4 bf16 (packed in v2u) -> 4 floats
__device__ inline void u2f(v2u u, float& a, float& b, float& c, float& d) {
    a = __uint_as_float(u.x << 16);
    b = __uint_as_float(u.x & 0xFFFF0000u);
    c = __uint_as_float(u.y << 16);
    d = __uint_as_float(u.y & 0xFFFF0000u);
}

__device__ inline float f16_val(uint32 e) {
    __half_raw h; h.x = (uint16)(e >> 16);
    return __half2float(__half(h));
}

// ---- fused prep: H->bf16 | zero counts | W->B-fragment layout ----
__global__ void prep(const float4* __restrict__ H, ushort4* __restrict__ Hb,
                     const float* __restrict__ W, uint16* __restrict__ Wfrag,
                     int* __restrict__ counts) {
    int b = blockIdx.x;
    int t = threadIdx.x;
    if (b < CB4) {
        int i = b * 256 + t;
        if (i < N4) {
            float4 v = H[i];
            ushort4 o;
            o.x = f32_to_bf16(v.x); o.y = f32_to_bf16(v.y);
            o.z = f32_to_bf16(v.z); o.w = f32_to_bf16(v.w);
            Hb[i] = o;
        }
    } else if (b < CB4 + NB_SCAN) {
        int i = (b - CB4) * 256 + t;
        if (i < NN) counts[i] = 0;
    } else {
        int idx = (b - CB4 - NB_SCAN) * 256 + t;   // 0..1151 = bt*64+lane
        if (idx < 18 * 64) {
            int bt = idx >> 6, lane = idx & 63;
            int nt = bt / 3, kc = bt % 3;
            int col = nt * 16 + (lane & 15);
            int kbase = kc * 32 + (lane >> 4) * 8;
            uint16 tmp[8];
            #pragma unroll
            for (int j = 0; j < 8; ++j) tmp[j] = f32_to_bf16(W[(kbase + j) * D + col]);
            uint32* dst = (uint32*)(Wfrag + ((size_t)bt * 64 + lane) * 8);
            const uint32* src = (const uint32*)tmp;
            #pragma unroll
            for (int j = 0; j < 4; ++j) dst[j] = src[j];
        }
    }
}

// ---------------- CSR build (two-phase, slot-based — R6 scheme) --------------
__global__ void hist_slots(const int* __restrict__ rows, int* __restrict__ counts,
                           int* __restrict__ slot) {
    int e = blockIdx.x * blockDim.x + threadIdx.x;
    if (e < NE) slot[e] = atomicAdd(&counts[rows[e]], 1);
}

__global__ void scan_p1(const int* __restrict__ counts, int* __restrict__ partials) {
    __shared__ int red[256];
    int t = threadIdx.x;
    int i = blockIdx.x * 256 + t;
    red[t] = (i < NN) ? counts[i] : 0;
    __syncthreads();
    for (int off = 128; off > 0; off >>= 1) {
        if (t < off) red[t] += red[t + off];
        __syncthreads();
    }
    if (t == 0) partials[blockIdx.x] = red[0];
}

// each block scans partials redundantly + local scan -> row_ptr
__global__ void scan_p23(const int* __restrict__ counts, const int* __restrict__ partials,
                         int* __restrict__ row_ptr) {
    __shared__ int pp[256];
    __shared__ int sh[256];
    int t = threadIdx.x;
    pp[t] = (t < NB_SCAN) ? partials[t] : 0;
    __syncthreads();
    for (int off = 1; off < 256; off <<= 1) {
        int u = (t >= off) ? pp[t - off] : 0;
        __syncthreads();
        pp[t] += u;
        __syncthreads();
    }
    int blk_off = (blockIdx.x == 0) ? 0 : pp[blockIdx.x - 1];
    int i = blockIdx.x * 256 + t;
    int v = (i < NN) ? counts[i] : 0;
    sh[t] = v;
    __syncthreads();
    for (int off = 1; off < 256; off <<= 1) {
        int u = (t >= off) ? sh[t - off] : 0;
        __syncthreads();
        sh[t] += u;
        __syncthreads();
    }
    int excl = sh[t] - v + blk_off;
    if (i < NN) row_ptr[i] = excl;
    if (i == NN - 1) row_ptr[NN] = excl + v;
}

// edge = col (low 16) | f16(val) (high 16); p = row_ptr[row] + slot (no atomics)
__global__ void fill_edges(const int* __restrict__ rows, const int* __restrict__ cols,
                           const float* __restrict__ vals, const int* __restrict__ row_ptr,
                           const int* __restrict__ slot, uint32* __restrict__ edges) {
    int e = blockIdx.x * blockDim.x + threadIdx.x;
    if (e < NE) {
        int p = row_ptr[rows[e]] + slot[e];
        __half_raw hr = __half_raw(__float2half(vals[e]));
        edges[p] = (uint32)(cols[e] & 0xFFFF) | ((uint32)hr.x << 16);
    }
}

// ---- SpMM (all bf16): Yb = bf16( ca*A + cb*B + scale * sum val * Xb[col] ) --
// 32 lanes per row; lanes 0..23 own 4 feats (8 B loads). Streams (A,B reads,
// Yb write) are nontemporal to keep Xb resident in L2 for the gathers.
__global__ void spmm(const int* __restrict__ row_ptr, const uint32* __restrict__ edges,
                     const uint16* __restrict__ Xb, const uint16* __restrict__ A,
                     const uint16* __restrict__ B, uint16* __restrict__ Yb,
                     float scale, float ca, float cb) {
    int tid  = threadIdx.x;
    int lane = tid & 31;
    int g    = tid >> 5;
    int r = blockIdx.x * 8 + g;
    if (r >= NN) return;
    if (lane >= 24) return;                       // exec-masked idle lanes

    const v2u* xbase = (const v2u*)Xb;            // row stride = 24 v2u

    v2u av = __builtin_nontemporal_load((const v2u*)(A + (size_t)r * D) + lane);
    v2u bv = __builtin_nontemporal_load((const v2u*)(B + (size_t)r * D) + lane);
    float a0,a1,a2,a3,b0,b1,b2,b3;
    u2f(av, a0,a1,a2,a3);
    u2f(bv, b0,b1,b2,b3);
    float ax = ca*a0 + cb*b0;
    float ay = ca*a1 + cb*b1;
    float az = ca*a2 + cb*b2;
    float aw = ca*a3 + cb*b3;

    int s = row_ptr[r];
    int e = row_ptr[r + 1];
    int i = s;
    for (; i + 7 < e; i += 8) {
        uint32 ee[8];
        #pragma unroll
        for (int j = 0; j < 8; ++j) ee[j] = edges[i + j];
        v2u xx[8];
        #pragma unroll
        for (int j = 0; j < 8; ++j)
            xx[j] = xbase[(size_t)(ee[j] & 0xFFFF) * 24 + lane];
        #pragma unroll
        for (int j = 0; j < 8; ++j) {
            float v = scale * f16_val(ee[j]);
            float x0,x1,x2,x3;
            u2f(xx[j], x0,x1,x2,x3);
            ax += v*x0; ay += v*x1; az += v*x2; aw += v*x3;
        }
    }
    for (; i + 3 < e; i += 4) {
        uint32 ee[4];
        #pragma unroll
        for (int j = 0; j < 4; ++j) ee[j] = edges[i + j];
        v2u xx[4];
        #pragma unroll
        for (int j = 0; j < 4; ++j)
            xx[j] = xbase[(size_t)(ee[j] & 0xFFFF) * 24 + lane];
        #pragma unroll
        for (int j = 0; j < 4; ++j) {
            float v = scale * f16_val(ee[j]);
            float x0,x1,x2,x3;
            u2f(xx[j], x0,x1,x2,x3);
            ax += v*x0; ay += v*x1; az += v*x2; aw += v*x3;
        }
    }
    for (; i < e; ++i) {
        uint32 e0 = edges[i];
        float v = scale * f16_val(e0);
        v2u x = xbase[(size_t)(e0 & 0xFFFF) * 24 + lane];
        float x0,x1,x2,x3;
        u2f(x, x0,x1,x2,x3);
        ax += v*x0; ay += v*x1; az += v*x2; aw += v*x3;
    }

    v2u o;
    o.x = (uint32)f32_to_bf16(ax) | ((uint32)f32_to_bf16(ay) << 16);
    o.y = (uint32)f32_to_bf16(az) | ((uint32)f32_to_bf16(aw) << 16);
    __builtin_nontemporal_store(o, (v2u*)(Yb + (size_t)r * D) + lane);
}

// ---- out = Sb @ W + bias via MFMA; one wave per 16-row strip (grid-stride) --
__global__ void mfma_gemm(const uint16* __restrict__ Sb, const uint16* __restrict__ Wfrag,
                          const float* __restrict__ bias, float* __restrict__ out) {
    int tid   = threadIdx.x;
    int lane  = tid & 63;
    int wv    = blockIdx.x * (blockDim.x >> 6) + (tid >> 6);
    int nwv   = gridDim.x * (blockDim.x >> 6);
    int col   = lane & 15;
    int quad  = lane >> 4;

    v8s wf[6][3];
    #pragma unroll
    for (int nt = 0; nt < 6; ++nt)
        #pragma unroll
        for (int kc = 0; kc < 3; ++kc)
            wf[nt][kc] = ((const v8s*)Wfrag)[(nt * 3 + kc) * 64 + lane];

    float bi[6];
    #pragma unroll
    for (int nt = 0; nt < 6; ++nt) bi[nt] = bias[nt * 16 + col];

    for (int s = wv; s < NN / 16; s += nwv) {
        int r0 = s * 16;
        const uint16* arow = Sb + (size_t)(r0 + col) * D + quad * 8;
        v8s a0 = *((const v8s*)(arow));
        v8s a1 = *((const v8s*)(arow + 32));
        v8s a2 = *((const v8s*)(arow + 64));
        v4f acc[6];
        #pragma unroll
        for (int nt = 0; nt < 6; ++nt) {
            v4f c = {0.f, 0.f, 0.f, 0.f};
            c = __builtin_amdgcn_mfma_f32_16x16x32_bf16(a0, wf[nt][0], c, 0, 0, 0);
            c = __builtin_amdgcn_mfma_f32_16x16x32_bf16(a1, wf[nt][1], c, 0, 0, 0);
            c = __builtin_amdgcn_mfma_f32_16x16x32_bf16(a2, wf[nt][2], c, 0, 0, 0);
            acc[nt] = c;
        }
        #pragma unroll
        for (int nt = 0; nt < 6; ++nt) {
            float* o = out + (size_t)(r0 + quad * 4) * D + nt * 16 + col;
            o[0 * D] = acc[nt][0] + bi[nt];
            o[1 * D] = acc[nt][1] + bi[nt];
            o[2 * D] = acc[nt][2] + bi[nt];
            o[3 * D] = acc[nt][3] + bi[nt];
        }
    }
}

extern "C" void kernel_launch(void* const* d_in, const int* in_sizes, int n_in,
                              void* d_out, int out_size, void* d_ws, size_t ws_size,
                              hipStream_t stream) {
    const int*   rows = (const int*)d_in[0];
    const int*   cols = (const int*)d_in[1];
    const float* vals = (const float*)d_in[2];
    const float* H    = (const float*)d_in[3];
    const float* W    = (const float*)d_in[4];
    const float* bias = (const float*)d_in[5];
    float* out = (float*)d_out;

    char* ws = (char*)d_ws;
    uint16* Hb       = (uint16*)ws;  ws += (size_t)NN * D * 2;   // 9.6 MB
    uint16* T1b      = (uint16*)ws;  ws += (size_t)NN * D * 2;   // later Sb
    uint16* T2b      = (uint16*)ws;  ws += (size_t)NN * D * 2;   // slot aliases here
    uint32* edges    = (uint32*)ws;  ws += (size_t)NE * 4;       // 3.2 MB
    uint16* Wfrag    = (uint16*)ws;  ws += (size_t)18 * 64 * 8 * 2;
    int*    counts   = (int*)ws;     ws += (size_t)NN * 4;
    int*    row_ptr  = (int*)ws;     ws += (size_t)(NN + 1) * 4;
    int*    partials = (int*)ws;     ws += 256 * 4;
    int*    slot     = (int*)T2b;    // dead before spmm pass 2 writes T2b
    uint16* Sb       = T1b;          // T1b dead after pass 2 reads it

    const int eb = (NE + 255) / 256;

    prep<<<CB4 + NB_SCAN + WFRAG_BLKS, 256, 0, stream>>>(
        (const float4*)H, (ushort4*)Hb, W, Wfrag, counts);
    hist_slots<<<eb, 256, 0, stream>>>(rows, counts, slot);
    scan_p1<<<NB_SCAN, 256, 0, stream>>>(counts, partials);
    scan_p23<<<NB_SCAN, 256, 0, stream>>>(counts, partials, row_ptr);
    fill_edges<<<eb, 256, 0, stream>>>(rows, cols, vals, row_ptr, slot, edges);

    const int sb = (NN + 7) / 8;

    // T1 = 2*spmm(H) - H
    spmm<<<sb, 256, 0, stream>>>(row_ptr, edges, Hb, Hb, Hb, T1b, 2.0f, -1.0f, 0.0f);
    // T2 = 4*spmm(T1) - 2*T1 - H
    spmm<<<sb, 256, 0, stream>>>(row_ptr, edges, T1b, T1b, Hb, T2b, 4.0f, -2.0f, -1.0f);
    // Sb = 4*spmm(T2) + H - T2   (= H+T1+T2+T3)
    spmm<<<sb, 256, 0, stream>>>(row_ptr, edges, T2b, Hb, T2b, Sb, 4.0f, 1.0f, -1.0f);
    // out = Sb @ W + bias  (MFMA)
    mfma_gemm<<<391, 256, 0, stream>>>(Sb, Wfrag, bias, out);
}

// Round 10
// 231.364 us; speedup vs baseline: 1.2017x; 1.0252x over previous
//
#include <hip/hip_runtime.h>
#include <hip/hip_fp16.h>

#define NN 50000
#define NE 800000
#define D  96
#define NB_SCAN 196   // ceil(NN/256)
#define N4 (NN * D / 4)
#define CB4 ((N4 + 255) / 256)
#define WFRAG_BLKS 5  // ceil(18*64/256)

typedef unsigned int   uint32;
typedef unsigned short uint16;
typedef short  v8s __attribute__((ext_vector_type(8)));  // 8 bf16 (4 VGPRs)
typedef float  v4f __attribute__((ext_vector_type(4)));  // MFMA accumulator
typedef unsigned int v2u __attribute__((ext_vector_type(2)));
typedef unsigned int v4u __attribute__((ext_vector_type(4)));

__device__ inline uint16 f32_to_bf16(float f) {          // round-nearest-even
    uint32 u = __float_as_uint(f);
    u += 0x7FFF + ((u >> 16) & 1);
    return (uint16)(u >> 16);
}

// unpack 4 bf16 (packed in v2u) -> 4 floats
__device__ inline void u2f(v2u u, float& a, float& b, float& c, float& d) {
    a = __uint_as_float(u.x << 16);
    b = __uint_as_float(u.x & 0xFFFF0000u);
    c = __uint_as_float(u.y << 16);
    d = __uint_as_float(u.y & 0xFFFF0000u);
}

__device__ inline float f16_val(uint32 e) {
    __half_raw h; h.x = (uint16)(e >> 16);
    return __half2float(__half(h));
}

// combine one packed bf16 pair from each U: s = 12*u1 - 40*u2 + 32*u3, repack
__device__ inline uint32 comb2(uint32 u1, uint32 u2, uint32 u3) {
    float a1 = __uint_as_float(u1 << 16), b1 = __uint_as_float(u1 & 0xFFFF0000u);
    float a2 = __uint_as_float(u2 << 16), b2 = __uint_as_float(u2 & 0xFFFF0000u);
    float a3 = __uint_as_float(u3 << 16), b3 = __uint_as_float(u3 & 0xFFFF0000u);
    float sa = 12.f * a1 - 40.f * a2 + 32.f * a3;
    float sb = 12.f * b1 - 40.f * b2 + 32.f * b3;
    return (uint32)f32_to_bf16(sa) | ((uint32)f32_to_bf16(sb) << 16);
}

// ---- fused prep: H->bf16 | zero counts | W->B-fragment layout ----
__global__ void prep(const float4* __restrict__ H, ushort4* __restrict__ Hb,
                     const float* __restrict__ W, uint16* __restrict__ Wfrag,
                     int* __restrict__ counts) {
    int b = blockIdx.x;
    int t = threadIdx.x;
    if (b < CB4) {
        int i = b * 256 + t;
        if (i < N4) {
            float4 v = H[i];
            ushort4 o;
            o.x = f32_to_bf16(v.x); o.y = f32_to_bf16(v.y);
            o.z = f32_to_bf16(v.z); o.w = f32_to_bf16(v.w);
            Hb[i] = o;
        }
    } else if (b < CB4 + NB_SCAN) {
        int i = (b - CB4) * 256 + t;
        if (i < NN) counts[i] = 0;
    } else {
        int idx = (b - CB4 - NB_SCAN) * 256 + t;   // 0..1151 = bt*64+lane
        if (idx < 18 * 64) {
            int bt = idx >> 6, lane = idx & 63;
            int nt = bt / 3, kc = bt % 3;
            int col = nt * 16 + (lane & 15);
            int kbase = kc * 32 + (lane >> 4) * 8;
            uint16 tmp[8];
            #pragma unroll
            for (int j = 0; j < 8; ++j) tmp[j] = f32_to_bf16(W[(kbase + j) * D + col]);
            uint32* dst = (uint32*)(Wfrag + ((size_t)bt * 64 + lane) * 8);
            const uint32* src = (const uint32*)tmp;
            #pragma unroll
            for (int j = 0; j < 4; ++j) dst[j] = src[j];
        }
    }
}

// ---------------- CSR build (two-phase, slot-based) ----------------
__global__ void hist_slots(const int* __restrict__ rows, int* __restrict__ counts,
                           int* __restrict__ slot) {
    int e = blockIdx.x * blockDim.x + threadIdx.x;
    if (e < NE) slot[e] = atomicAdd(&counts[rows[e]], 1);
}

__global__ void scan_p1(const int* __restrict__ counts, int* __restrict__ partials) {
    __shared__ int red[256];
    int t = threadIdx.x;
    int i = blockIdx.x * 256 + t;
    red[t] = (i < NN) ? counts[i] : 0;
    __syncthreads();
    for (int off = 128; off > 0; off >>= 1) {
        if (t < off) red[t] += red[t + off];
        __syncthreads();
    }
    if (t == 0) partials[blockIdx.x] = red[0];
}

__global__ void scan_p23(const int* __restrict__ counts, const int* __restrict__ partials,
                         int* __restrict__ row_ptr) {
    __shared__ int pp[256];
    __shared__ int sh[256];
    int t = threadIdx.x;
    pp[t] = (t < NB_SCAN) ? partials[t] : 0;
    __syncthreads();
    for (int off = 1; off < 256; off <<= 1) {
        int u = (t >= off) ? pp[t - off] : 0;
        __syncthreads();
        pp[t] += u;
        __syncthreads();
    }
    int blk_off = (blockIdx.x == 0) ? 0 : pp[blockIdx.x - 1];
    int i = blockIdx.x * 256 + t;
    int v = (i < NN) ? counts[i] : 0;
    sh[t] = v;
    __syncthreads();
    for (int off = 1; off < 256; off <<= 1) {
        int u = (t >= off) ? sh[t - off] : 0;
        __syncthreads();
        sh[t] += u;
        __syncthreads();
    }
    int excl = sh[t] - v + blk_off;
    if (i < NN) row_ptr[i] = excl;
    if (i == NN - 1) row_ptr[NN] = excl + v;
}

// edge = col (low 16) | f16(val) (high 16); p = row_ptr[row] + slot (no atomics)
__global__ void fill_edges(const int* __restrict__ rows, const int* __restrict__ cols,
                           const float* __restrict__ vals, const int* __restrict__ row_ptr,
                           const int* __restrict__ slot, uint32* __restrict__ edges) {
    int e = blockIdx.x * blockDim.x + threadIdx.x;
    if (e < NE) {
        int p = row_ptr[rows[e]] + slot[e];
        __half_raw hr = __half_raw(__float2half(vals[e]));
        edges[p] = (uint32)(cols[e] & 0xFFFF) | ((uint32)hr.x << 16);
    }
}

// ---- pure SpMM: Yb = bf16( sum val * Xb[col] )  (no affine terms) ----------
// 32 lanes per row; lanes 0..23 own 4 feats (8 B gathers).
__global__ void spmm(const int* __restrict__ row_ptr, const uint32* __restrict__ edges,
                     const uint16* __restrict__ Xb, uint16* __restrict__ Yb) {
    int tid  = threadIdx.x;
    int lane = tid & 31;
    int g    = tid >> 5;
    int r = blockIdx.x * 8 + g;
    if (r >= NN) return;
    if (lane >= 24) return;                       // exec-masked idle lanes

    const v2u* xbase = (const v2u*)Xb;            // row stride = 24 v2u

    float ax = 0.f, ay = 0.f, az = 0.f, aw = 0.f;

    int s = row_ptr[r];
    int e = row_ptr[r + 1];
    int i = s;
    for (; i + 7 < e; i += 8) {
        uint32 ee[8];
        #pragma unroll
        for (int j = 0; j < 8; ++j) ee[j] = edges[i + j];
        v2u xx[8];
        #pragma unroll
        for (int j = 0; j < 8; ++j)
            xx[j] = xbase[(size_t)(ee[j] & 0xFFFF) * 24 + lane];
        #pragma unroll
        for (int j = 0; j < 8; ++j) {
            float v = f16_val(ee[j]);
            float x0,x1,x2,x3;
            u2f(xx[j], x0,x1,x2,x3);
            ax += v*x0; ay += v*x1; az += v*x2; aw += v*x3;
        }
    }
    for (; i + 3 < e; i += 4) {
        uint32 ee[4];
        #pragma unroll
        for (int j = 0; j < 4; ++j) ee[j] = edges[i + j];
        v2u xx[4];
        #pragma unroll
        for (int j = 0; j < 4; ++j)
            xx[j] = xbase[(size_t)(ee[j] & 0xFFFF) * 24 + lane];
        #pragma unroll
        for (int j = 0; j < 4; ++j) {
            float v = f16_val(ee[j]);
            float x0,x1,x2,x3;
            u2f(xx[j], x0,x1,x2,x3);
            ax += v*x0; ay += v*x1; az += v*x2; aw += v*x3;
        }
    }
    for (; i < e; ++i) {
        uint32 e0 = edges[i];
        float v = f16_val(e0);
        v2u x = xbase[(size_t)(e0 & 0xFFFF) * 24 + lane];
        float x0,x1,x2,x3;
        u2f(x, x0,x1,x2,x3);
        ax += v*x0; ay += v*x1; az += v*x2; aw += v*x3;
    }

    v2u o;
    o.x = (uint32)f32_to_bf16(ax) | ((uint32)f32_to_bf16(ay) << 16);
    o.y = (uint32)f32_to_bf16(az) | ((uint32)f32_to_bf16(aw) << 16);
    __builtin_nontemporal_store(o, (v2u*)(Yb + (size_t)r * D) + lane);
}

// ---- out = (12U1-40U2+32U3) @ W + bias via MFMA; one wave per 16-row strip --
__global__ void mfma_gemm(const uint16* __restrict__ U1, const uint16* __restrict__ U2,
                          const uint16* __restrict__ U3, const uint16* __restrict__ Wfrag,
                          const float* __restrict__ bias, float* __restrict__ out) {
    int tid   = threadIdx.x;
    int lane  = tid & 63;
    int wv    = blockIdx.x * (blockDim.x >> 6) + (tid >> 6);
    int nwv   = gridDim.x * (blockDim.x >> 6);
    int col   = lane & 15;
    int quad  = lane >> 4;

    v8s wf[6][3];
    #pragma unroll
    for (int nt = 0; nt < 6; ++nt)
        #pragma unroll
        for (int kc = 0; kc < 3; ++kc)
            wf[nt][kc] = ((const v8s*)Wfrag)[(nt * 3 + kc) * 64 + lane];

    float bi[6];
    #pragma unroll
    for (int nt = 0; nt < 6; ++nt) bi[nt] = bias[nt * 16 + col];

    for (int s = wv; s < NN / 16; s += nwv) {
        int r0 = s * 16;
        size_t base = (size_t)(r0 + col) * D + quad * 8;   // in bf16 elems
        v8s a[3];
        #pragma unroll
        for (int kc = 0; kc < 3; ++kc) {
            v4u u1 = *(const v4u*)(U1 + base + kc * 32);
            v4u u2 = *(const v4u*)(U2 + base + kc * 32);
            v4u u3 = *(const v4u*)(U3 + base + kc * 32);
            v4u sres;
            #pragma unroll
            for (int j = 0; j < 4; ++j) sres[j] = comb2(u1[j], u2[j], u3[j]);
            a[kc] = __builtin_bit_cast(v8s, sres);
        }
        v4f acc[6];
        #pragma unroll
        for (int nt = 0; nt < 6; ++nt) {
            v4f c = {0.f, 0.f, 0.f, 0.f};
            c = __builtin_amdgcn_mfma_f32_16x16x32_bf16(a[0], wf[nt][0], c, 0, 0, 0);
            c = __builtin_amdgcn_mfma_f32_16x16x32_bf16(a[1], wf[nt][1], c, 0, 0, 0);
            c = __builtin_amdgcn_mfma_f32_16x16x32_bf16(a[2], wf[nt][2], c, 0, 0, 0);
            acc[nt] = c;
        }
        #pragma unroll
        for (int nt = 0; nt < 6; ++nt) {
            float* o = out + (size_t)(r0 + quad * 4) * D + nt * 16 + col;
            o[0 * D] = acc[nt][0] + bi[nt];
            o[1 * D] = acc[nt][1] + bi[nt];
            o[2 * D] = acc[nt][2] + bi[nt];
            o[3 * D] = acc[nt][3] + bi[nt];
        }
    }
}

extern "C" void kernel_launch(void* const* d_in, const int* in_sizes, int n_in,
                              void* d_out, int out_size, void* d_ws, size_t ws_size,
                              hipStream_t stream) {
    const int*   rows = (const int*)d_in[0];
    const int*   cols = (const int*)d_in[1];
    const float* vals = (const float*)d_in[2];
    const float* H    = (const float*)d_in[3];
    const float* W    = (const float*)d_in[4];
    const float* bias = (const float*)d_in[5];
    float* out = (float*)d_out;

    char* ws = (char*)d_ws;
    uint16* Hb       = (uint16*)ws;  ws += (size_t)NN * D * 2;   // 9.6 MB
    uint16* U1b      = (uint16*)ws;  ws += (size_t)NN * D * 2;
    uint16* U2b      = (uint16*)ws;  ws += (size_t)NN * D * 2;   // slot aliases here
    uint16* U3b      = (uint16*)ws;  ws += (size_t)NN * D * 2;
    uint32* edges    = (uint32*)ws;  ws += (size_t)NE * 4;       // 3.2 MB
    uint16* Wfrag    = (uint16*)ws;  ws += (size_t)18 * 64 * 8 * 2;
    int*    counts   = (int*)ws;     ws += (size_t)NN * 4;
    int*    row_ptr  = (int*)ws;     ws += (size_t)(NN + 1) * 4;
    int*    partials = (int*)ws;     ws += 256 * 4;
    int*    slot     = (int*)U2b;    // dead before spmm pass 2 writes U2b

    const int eb = (NE + 255) / 256;

    prep<<<CB4 + NB_SCAN + WFRAG_BLKS, 256, 0, stream>>>(
        (const float4*)H, (ushort4*)Hb, W, Wfrag, counts);
    hist_slots<<<eb, 256, 0, stream>>>(rows, counts, slot);
    scan_p1<<<NB_SCAN, 256, 0, stream>>>(counts, partials);
    scan_p23<<<NB_SCAN, 256, 0, stream>>>(counts, partials, row_ptr);
    fill_edges<<<eb, 256, 0, stream>>>(rows, cols, vals, row_ptr, slot, edges);

    const int sb = (NN + 7) / 8;

    // U1 = P H,  U2 = P U1,  U3 = P U2   (pure monomials)
    spmm<<<sb, 256, 0, stream>>>(row_ptr, edges, Hb,  U1b);
    spmm<<<sb, 256, 0, stream>>>(row_ptr, edges, U1b, U2b);
    spmm<<<sb, 256, 0, stream>>>(row_ptr, edges, U2b, U3b);
    // out = (12U1 - 40U2 + 32U3) @ W + bias   (= (T0+T1+T2+T3) @ W + bias)
    mfma_gemm<<<391, 256, 0, stream>>>(U1b, U2b, U3b, Wfrag, bias, out);
}